// Round 1
// baseline (451.141 us; speedup 1.0000x reference)
//
#include <hip/hip_runtime.h>

// ---------------------------------------------------------------------------
// Controller: 4-layer LSTM stack + two heads, bf16 MFMA GEMMs.
// P_X=512 P_H=1024 P_L=4 P_VT=512 P_ET=256 B=512 IN_DIM=2560
//
// ws layout (bytes):
//   Z_OFF   = 0         : z_buf   bf16 [4][512][2560]  (10,485,760 B)
//   HID_OFF = 10485760  : hidden  bf16 [512][4096]     ( 4,194,304 B)
//   GP_OFF  = 14680064  : partials f32, 2x512x4096 for layers (16,777,216 B)
//                         reused as 8x512x768 for heads (12,582,912 B)
// ---------------------------------------------------------------------------

typedef short    shortx8  __attribute__((ext_vector_type(8)));
typedef float    floatx16 __attribute__((ext_vector_type(16)));

__device__ __forceinline__ unsigned int f2bf1(float x) {
  unsigned int u = __float_as_uint(x);
  return (u + 0x7fffu + ((u >> 16) & 1u)) >> 16;   // RNE to bf16 bits
}
__device__ __forceinline__ unsigned int f2bf2(float lo, float hi) {
  return f2bf1(lo) | (f2bf1(hi) << 16);
}

// ---------------------------------------------------------------------------
// prep: z_buf[l][b][k] = bf16(concat(x, h_prev[l], zeros)) ; prev slice of
// layer 0 zeroed here, layers 1..3 prev slice written by lstm_pointwise.
// grid (640, 4) x 256 ; 8 elems/thread
// ---------------------------------------------------------------------------
__global__ __launch_bounds__(256) void prep_z(const float* __restrict__ x,
                                              const float* __restrict__ hp,
                                              unsigned short* __restrict__ z) {
  const int layer = blockIdx.y;
  const int idx   = blockIdx.x * 256 + threadIdx.x;  // 0 .. 512*320-1
  const int b     = idx / 320;
  const int kk    = (idx - b * 320) * 8;
  float v[8];
  if (kk < 512) {
    const float* s = x + (size_t)b * 512 + kk;
#pragma unroll
    for (int i = 0; i < 8; ++i) v[i] = s[i];
  } else if (kk < 1536) {
    const float* s = hp + ((size_t)layer * 512 + b) * 1024 + (kk - 512);
#pragma unroll
    for (int i = 0; i < 8; ++i) v[i] = s[i];
  } else {
    if (layer != 0) return;  // written later by lstm_pointwise(layer-1)
#pragma unroll
    for (int i = 0; i < 8; ++i) v[i] = 0.f;
  }
  uint4 o;
  o.x = f2bf2(v[0], v[1]); o.y = f2bf2(v[2], v[3]);
  o.z = f2bf2(v[4], v[5]); o.w = f2bf2(v[6], v[7]);
  *(uint4*)(z + ((size_t)layer * 512 + b) * 2560 + kk) = o;
}

// ---------------------------------------------------------------------------
// GEMM: C[b,n] (fp32 partial per k-split) = sum_k A[b,k](bf16) * W[n,k](fp32)
// BM=BN=128, BK=64, 256 thr = 4 waves (2x2 of 64x64), mfma_f32_32x32x16_bf16.
// LDS k-groups XOR-swizzled by (row&7) -> conflict-free ds_read_b128.
// grid: (ksplits, ntiles, mtiles)
// ---------------------------------------------------------------------------
__global__ __launch_bounds__(256) void gemm_bt_split(
    const unsigned short* __restrict__ A, int lda,
    const float* __restrict__ B0, int nb0,      // first nb0 n-tiles from B0
    const float* __restrict__ B1,               // remaining n-tiles
    float* __restrict__ Cp, int ldc, int mtotal, int ktiles) {
  __shared__ __align__(16) unsigned short As[128 * 64];
  __shared__ __align__(16) unsigned short Bs[128 * 64];
  const int tid  = threadIdx.x;
  const int lane = tid & 63;
  const int wave = tid >> 6;
  const int mbase = blockIdx.z * 128;
  const int nt    = blockIdx.y;
  const int nbase = nt * 128;
  const float* Bb = (nt < nb0) ? (B0 + (size_t)nbase * lda)
                               : (B1 + (size_t)(nbase - nb0 * 128) * lda);
  const int k0 = blockIdx.x * (ktiles * 64);

  floatx16 acc[2][2];
#pragma unroll
  for (int a = 0; a < 2; ++a)
#pragma unroll
    for (int bb = 0; bb < 2; ++bb)
#pragma unroll
      for (int r = 0; r < 16; ++r) acc[a][bb][r] = 0.f;

  const int wm = (wave >> 1) * 64;
  const int wn = (wave & 1) * 64;
  const int arow = wave * 8 + (lane >> 3);  // A staging row (per round +32)
  const int akg  = lane & 7;                // A staging k-group
  const unsigned short* Ab = A + (size_t)mbase * lda;

  for (int kt = 0; kt < ktiles; ++kt) {
    const int kg = k0 + kt * 64;
    // ---- stage A (bf16, 16 KB): 4 rounds of 32 rows, 16B/lane -------------
#pragma unroll
    for (int r = 0; r < 4; ++r) {
      const int row = arow + r * 32;
      const uint4 av = *(const uint4*)(Ab + (size_t)row * lda + kg + akg * 8);
      *(uint4*)(As + row * 64 + ((akg ^ (row & 7)) * 8)) = av;
    }
    // ---- stage B (fp32 -> bf16, 32KB->16KB): 8 float4/thread --------------
#pragma unroll
    for (int j = 0; j < 8; ++j) {
      const int idx = j * 256 + tid;
      const int n   = idx >> 4;          // 0..127
      const int kc  = (idx & 15) * 4;    // 0..60
      const float4 bv = *(const float4*)(Bb + (size_t)n * lda + kg + kc);
      uint2 pk;
      pk.x = f2bf2(bv.x, bv.y);
      pk.y = f2bf2(bv.z, bv.w);
      const int g    = kc >> 3;
      const int half = kc & 4;           // 0 or 4 elems (8B half of group)
      *(uint2*)(Bs + n * 64 + ((g ^ (n & 7)) * 8) + half) = pk;
    }
    __syncthreads();
    // ---- compute: 4 ksteps of K=16 ----------------------------------------
#pragma unroll
    for (int ks = 0; ks < 4; ++ks) {
      const int gb = ks * 2 + (lane >> 5);  // logical k-group this lane reads
      shortx8 af[2], bf[2];
#pragma unroll
      for (int sm = 0; sm < 2; ++sm) {
        const int row = wm + sm * 32 + (lane & 31);
        af[sm] = *(const shortx8*)(As + row * 64 + ((gb ^ (row & 7)) * 8));
      }
#pragma unroll
      for (int sn = 0; sn < 2; ++sn) {
        const int row = wn + sn * 32 + (lane & 31);
        bf[sn] = *(const shortx8*)(Bs + row * 64 + ((gb ^ (row & 7)) * 8));
      }
#pragma unroll
      for (int sm = 0; sm < 2; ++sm)
#pragma unroll
        for (int sn = 0; sn < 2; ++sn)
          acc[sm][sn] = __builtin_amdgcn_mfma_f32_32x32x16_bf16(
              af[sm], bf[sn], acc[sm][sn], 0, 0, 0);
    }
    __syncthreads();
  }

  // epilogue: C/D layout col=lane&31, row=(r&3)+8*(r>>2)+4*(lane>>5)
  float* Co = Cp + (size_t)blockIdx.x * mtotal * ldc;
#pragma unroll
  for (int sm = 0; sm < 2; ++sm)
#pragma unroll
    for (int sn = 0; sn < 2; ++sn) {
      const int col = nbase + wn + sn * 32 + (lane & 31);
#pragma unroll
      for (int r = 0; r < 16; ++r) {
        const int row = mbase + wm + sm * 32 +
                        ((r & 3) + 8 * (r >> 2) + 4 * (lane >> 5));
        Co[(size_t)row * ldc + col] = acc[sm][sn][r];
      }
    }
}

// ---------------------------------------------------------------------------
// pointwise: g = gp0+gp1+bias ; LSTM cell ; h -> hidden (bf16) and z[l+1]
// grid 512 x 256 ; 4 elems/thread over [512][1024]
// ---------------------------------------------------------------------------
__global__ __launch_bounds__(256) void lstm_pointwise(
    const float* __restrict__ gp, const float* __restrict__ bg_l,
    const float* __restrict__ cp_l, unsigned short* __restrict__ hidden,
    unsigned short* __restrict__ znext, int layer) {
  const int idx = (blockIdx.x * 256 + threadIdx.x) * 4;
  const int b = idx >> 10;
  const int h = idx & 1023;
  const float* g0 = gp + (size_t)b * 4096;
  const float* g1 = gp + (size_t)512 * 4096 + (size_t)b * 4096;
  float4 vi = *(const float4*)(g0 + h);
  float4 vf = *(const float4*)(g0 + 1024 + h);
  float4 vo = *(const float4*)(g0 + 2048 + h);
  float4 vs = *(const float4*)(g0 + 3072 + h);
  const float4 wi = *(const float4*)(g1 + h);
  const float4 wf = *(const float4*)(g1 + 1024 + h);
  const float4 wo = *(const float4*)(g1 + 2048 + h);
  const float4 ws = *(const float4*)(g1 + 3072 + h);
  const float4 bi = *(const float4*)(bg_l + h);
  const float4 bff = *(const float4*)(bg_l + 1024 + h);
  const float4 bo = *(const float4*)(bg_l + 2048 + h);
  const float4 bs = *(const float4*)(bg_l + 3072 + h);
  const float4 cp = *(const float4*)(cp_l + (size_t)b * 1024 + h);

  float gi[4] = {vi.x + wi.x + bi.x, vi.y + wi.y + bi.y,
                 vi.z + wi.z + bi.z, vi.w + wi.w + bi.w};
  float gf[4] = {vf.x + wf.x + bff.x, vf.y + wf.y + bff.y,
                 vf.z + wf.z + bff.z, vf.w + wf.w + bff.w};
  float go[4] = {vo.x + wo.x + bo.x, vo.y + wo.y + bo.y,
                 vo.z + wo.z + bo.z, vo.w + wo.w + bo.w};
  float gs[4] = {vs.x + ws.x + bs.x, vs.y + ws.y + bs.y,
                 vs.z + ws.z + bs.z, vs.w + ws.w + bs.w};
  const float cc[4] = {cp.x, cp.y, cp.z, cp.w};
  float hn[4];
#pragma unroll
  for (int j = 0; j < 4; ++j) {
    const float ig = 1.f / (1.f + __expf(-gi[j]));
    const float fg = 1.f / (1.f + __expf(-gf[j]));
    const float og = 1.f / (1.f + __expf(-go[j]));
    const float sg = 1.f - 2.f / (__expf(2.f * gs[j]) + 1.f);
    const float c  = fg * cc[j] + ig * sg;
    const float tc = 1.f - 2.f / (__expf(2.f * c) + 1.f);
    hn[j] = og * tc;
  }
  uint2 o;
  o.x = f2bf2(hn[0], hn[1]);
  o.y = f2bf2(hn[2], hn[3]);
  *(uint2*)(hidden + (size_t)b * 4096 + layer * 1024 + h) = o;
  if (znext) *(uint2*)(znext + (size_t)b * 2560 + 1536 + h) = o;
}

// ---------------------------------------------------------------------------
// head reduce: sum 8 k-split partials + bias -> d_out (output then interface)
// grid (3, 512) x 256
// ---------------------------------------------------------------------------
__global__ __launch_bounds__(256) void head_reduce(
    const float* __restrict__ hp, const float* __restrict__ b_y,
    const float* __restrict__ b_E, float* __restrict__ out) {
  const int n = blockIdx.x * 256 + threadIdx.x;  // 0..767
  const int b = blockIdx.y;
  float s = 0.f;
#pragma unroll
  for (int ks = 0; ks < 8; ++ks) s += hp[(size_t)ks * 512 * 768 + (size_t)b * 768 + n];
  if (n < 512)
    out[(size_t)b * 512 + n] = s + b_y[n];
  else
    out[(size_t)512 * 512 + (size_t)b * 256 + (n - 512)] = s + b_E[n - 512];
}

// ---------------------------------------------------------------------------
extern "C" void kernel_launch(void* const* d_in, const int* in_sizes, int n_in,
                              void* d_out, int out_size, void* d_ws, size_t ws_size,
                              hipStream_t stream) {
  const float* x      = (const float*)d_in[0];
  const float* h_prev = (const float*)d_in[1];
  const float* c_prev = (const float*)d_in[2];
  const float* Wg     = (const float*)d_in[3];
  const float* bg     = (const float*)d_in[4];
  const float* W_y    = (const float*)d_in[5];
  const float* b_y    = (const float*)d_in[6];
  const float* W_E    = (const float*)d_in[7];
  const float* b_E    = (const float*)d_in[8];

  char* ws = (char*)d_ws;
  unsigned short* z      = (unsigned short*)(ws + 0);
  unsigned short* hidden = (unsigned short*)(ws + 10485760);
  float*          gpart  = (float*)(ws + 14680064);

  prep_z<<<dim3(640, 4), 256, 0, stream>>>(x, h_prev, z);

  for (int l = 0; l < 4; ++l) {
    gemm_bt_split<<<dim3(2, 32, 4), 256, 0, stream>>>(
        z + (size_t)l * 512 * 2560, 2560,
        Wg + (size_t)l * 4 * 1024 * 2560, 32, nullptr,
        gpart, 4096, 512, 20);
    lstm_pointwise<<<512, 256, 0, stream>>>(
        gpart, bg + (size_t)l * 4096, c_prev + (size_t)l * 512 * 1024,
        hidden, (l < 3) ? (z + (size_t)(l + 1) * 512 * 2560) : nullptr, l);
  }

  gemm_bt_split<<<dim3(8, 6, 4), 256, 0, stream>>>(
      hidden, 4096, W_y, 4, W_E, gpart, 768, 512, 8);
  head_reduce<<<dim3(3, 512), 256, 0, stream>>>(gpart, b_y, b_E, (float*)d_out);
}

// Round 2
// 404.914 us; speedup vs baseline: 1.1142x; 1.1142x over previous
//
#include <hip/hip_runtime.h>

// ---------------------------------------------------------------------------
// Controller: 4-layer LSTM stack + two heads.
// Restructured: z = [x, h_prev[l], prev_layer]; the K=1536 slice (x,h_prev)
// for ALL layers is one parallel GEMM (gemm_gates); only the K=1024
// prev-layer slice is sequential (gemm_seq_cell, LSTM cell fused in
// epilogue). Layer 0's prev contribution is exactly zero -> pure pointwise.
//
// ws layout (bytes):
//   A0     @ 0        : bf16 [4][512][1536]   6,291,456
//   G      @ 6291456  : f32  [4][512][4096]  33,554,432  (bias folded)
//   hidden @ 39845888 : bf16 [512][4096]      4,194,304
//   hpart  @ 44040192 : f32  [8][512][768]   12,582,912
// ---------------------------------------------------------------------------

typedef short    shortx8  __attribute__((ext_vector_type(8)));
typedef float    floatx16 __attribute__((ext_vector_type(16)));

__device__ __forceinline__ unsigned int f2bf1(float x) {
  unsigned int u = __float_as_uint(x);
  return (u + 0x7fffu + ((u >> 16) & 1u)) >> 16;   // RNE to bf16 bits
}
__device__ __forceinline__ unsigned int f2bf2(float lo, float hi) {
  return f2bf1(lo) | (f2bf1(hi) << 16);
}
__device__ __forceinline__ float sigm(float x) { return 1.f / (1.f + __expf(-x)); }
__device__ __forceinline__ float tanh_(float x) { return 1.f - 2.f / (__expf(2.f * x) + 1.f); }

// ---------------------------------------------------------------------------
// prep_a0: A0[l][b][0:1536] = bf16(x[b] ++ h_prev[l][b]).  grid (384,4) x 256
// ---------------------------------------------------------------------------
__global__ __launch_bounds__(256) void prep_a0(const float* __restrict__ x,
                                               const float* __restrict__ hp,
                                               unsigned short* __restrict__ A0) {
  const int l   = blockIdx.y;
  const int idx = blockIdx.x * 256 + threadIdx.x;   // < 512*192
  const int b   = idx / 192;
  const int kk  = (idx - b * 192) * 8;
  float v[8];
  if (kk < 512) {
    const float* s = x + (size_t)b * 512 + kk;
#pragma unroll
    for (int i = 0; i < 8; ++i) v[i] = s[i];
  } else {
    const float* s = hp + ((size_t)l * 512 + b) * 1024 + (kk - 512);
#pragma unroll
    for (int i = 0; i < 8; ++i) v[i] = s[i];
  }
  uint4 o;
  o.x = f2bf2(v[0], v[1]); o.y = f2bf2(v[2], v[3]);
  o.z = f2bf2(v[4], v[5]); o.w = f2bf2(v[6], v[7]);
  *(uint4*)(A0 + ((size_t)l * 512 + b) * 1536 + kk) = o;
}

// ---------------------------------------------------------------------------
// gemm_gates: G[l][b][n] = bg[l][n] + sum_{k<1536} A0[l][b][k] * Wg[l][n][k]
// BM=BN=128 BK=64, 256 thr (2x2 waves of 64x64), double-buffered LDS (64KB,
// 2 blocks/CU), register prefetch, one barrier per ktile. grid (4,32,4).
// ---------------------------------------------------------------------------
__global__ __launch_bounds__(256, 2) void gemm_gates(
    const unsigned short* __restrict__ A0, const float* __restrict__ Wg,
    const float* __restrict__ bg, float* __restrict__ G) {
  __shared__ __align__(16) unsigned short As[2][128 * 64];
  __shared__ __align__(16) unsigned short Bs[2][128 * 64];
  const int tid = threadIdx.x, lane = tid & 63, wave = tid >> 6;
  const int mbase = blockIdx.x * 128;
  const int nbase = blockIdx.y * 128;
  const int l     = blockIdx.z;
  const unsigned short* Ab = A0 + ((size_t)l * 512 + mbase) * 1536;
  const float*          Bb = Wg + (size_t)l * 4096 * 2560 + (size_t)nbase * 2560;
  const int arow = wave * 8 + (lane >> 3);
  const int akg  = lane & 7;

  uint4  apf[4];
  float4 bpf[8];
  auto loadT = [&](int kt) {
    const int kg = kt * 64;
#pragma unroll
    for (int r = 0; r < 4; ++r)
      apf[r] = *(const uint4*)(Ab + (size_t)(arow + r * 32) * 1536 + kg + akg * 8);
#pragma unroll
    for (int j = 0; j < 8; ++j) {
      const int idx = j * 256 + tid;
      bpf[j] = *(const float4*)(Bb + (size_t)(idx >> 4) * 2560 + kg + (idx & 15) * 4);
    }
  };
  auto storeT = [&](int buf) {
#pragma unroll
    for (int r = 0; r < 4; ++r) {
      const int row = arow + r * 32;
      *(uint4*)(&As[buf][row * 64 + ((akg ^ (row & 7)) * 8)]) = apf[r];
    }
#pragma unroll
    for (int j = 0; j < 8; ++j) {
      const int idx = j * 256 + tid;
      const int n = idx >> 4, kc = (idx & 15) * 4;
      uint2 pk;
      pk.x = f2bf2(bpf[j].x, bpf[j].y);
      pk.y = f2bf2(bpf[j].z, bpf[j].w);
      *(uint2*)(&Bs[buf][n * 64 + (((kc >> 3) ^ (n & 7)) * 8) + (kc & 4)]) = pk;
    }
  };

  floatx16 acc[2][2];
#pragma unroll
  for (int a = 0; a < 2; ++a)
#pragma unroll
    for (int b2 = 0; b2 < 2; ++b2)
#pragma unroll
      for (int r = 0; r < 16; ++r) acc[a][b2][r] = 0.f;

  const int wm = (wave >> 1) * 64, wn = (wave & 1) * 64;
  loadT(0);
  storeT(0);
  __syncthreads();
  for (int kt = 0; kt < 24; ++kt) {
    if (kt + 1 < 24) loadT(kt + 1);
    const int cb = kt & 1;
#pragma unroll
    for (int ks = 0; ks < 4; ++ks) {
      const int gb = ks * 2 + (lane >> 5);
      shortx8 af[2], bfv[2];
#pragma unroll
      for (int sm = 0; sm < 2; ++sm) {
        const int row = wm + sm * 32 + (lane & 31);
        af[sm] = *(const shortx8*)(&As[cb][row * 64 + ((gb ^ (row & 7)) * 8)]);
      }
#pragma unroll
      for (int sn = 0; sn < 2; ++sn) {
        const int row = wn + sn * 32 + (lane & 31);
        bfv[sn] = *(const shortx8*)(&Bs[cb][row * 64 + ((gb ^ (row & 7)) * 8)]);
      }
#pragma unroll
      for (int sm = 0; sm < 2; ++sm)
#pragma unroll
        for (int sn = 0; sn < 2; ++sn)
          acc[sm][sn] = __builtin_amdgcn_mfma_f32_32x32x16_bf16(
              af[sm], bfv[sn], acc[sm][sn], 0, 0, 0);
    }
    if (kt + 1 < 24) storeT((kt + 1) & 1);
    __syncthreads();
  }

  const float* bgl = bg + (size_t)l * 4096;
  float* Gl = G + ((size_t)l * 512 + mbase) * 4096;
#pragma unroll
  for (int sm = 0; sm < 2; ++sm)
#pragma unroll
    for (int sn = 0; sn < 2; ++sn) {
      const int col = nbase + wn + sn * 32 + (lane & 31);
      const float bias = bgl[col];
#pragma unroll
      for (int r = 0; r < 16; ++r) {
        const int row = wm + sm * 32 + ((r & 3) + 8 * (r >> 2) + 4 * (lane >> 5));
        Gl[(size_t)row * 4096 + col] = acc[sm][sn][r] + bias;
      }
    }
}

// ---------------------------------------------------------------------------
// cell0: layer 0 has zero prev-layer input -> pure pointwise on G[0].
// grid 512 x 256, 4 elems/thread.
// ---------------------------------------------------------------------------
__global__ __launch_bounds__(256) void cell0(const float* __restrict__ G,
                                             const float* __restrict__ cp_l,
                                             unsigned short* __restrict__ hidden) {
  const int idx = (blockIdx.x * 256 + threadIdx.x) * 4;
  const int b = idx >> 10, h = idx & 1023;
  const float* g0 = G + (size_t)b * 4096;
  const float4 vi = *(const float4*)(g0 + h);
  const float4 vf = *(const float4*)(g0 + 1024 + h);
  const float4 vo = *(const float4*)(g0 + 2048 + h);
  const float4 vs = *(const float4*)(g0 + 3072 + h);
  const float4 cp = *(const float4*)(cp_l + (size_t)b * 1024 + h);
  const float gi[4] = {vi.x, vi.y, vi.z, vi.w};
  const float gf[4] = {vf.x, vf.y, vf.z, vf.w};
  const float go[4] = {vo.x, vo.y, vo.z, vo.w};
  const float gs[4] = {vs.x, vs.y, vs.z, vs.w};
  const float cc[4] = {cp.x, cp.y, cp.z, cp.w};
  float hn[4];
#pragma unroll
  for (int j = 0; j < 4; ++j) {
    const float c = sigm(gf[j]) * cc[j] + sigm(gi[j]) * tanh_(gs[j]);
    hn[j] = sigm(go[j]) * tanh_(c);
  }
  uint2 o;
  o.x = f2bf2(hn[0], hn[1]);
  o.y = f2bf2(hn[2], hn[3]);
  *(uint2*)(hidden + (size_t)b * 4096 + h) = o;
}

// ---------------------------------------------------------------------------
// gemm_seq_cell: Gp = Wg[l][:,:,1536:2560] . h_{l-1}  (K=1024), then fused
// LSTM cell. Block = BM=128 rows x BN=64 cols where n_local = g*16+hh
// (4 gates x 16 h) -> epilogue holds all 4 gates for (b,hh), cell computed
// after an LDS transpose. 512 thr = 8 waves (4m x 2n of 32x32), dbuf LDS.
// grid (4 m, 64 h-tiles).
// ---------------------------------------------------------------------------
__global__ __launch_bounds__(512, 2) void gemm_seq_cell(
    const unsigned short* __restrict__ hidden_ro, const float* __restrict__ Wg,
    const float* __restrict__ G, const float* __restrict__ c_prev,
    unsigned short* __restrict__ hidden_w, int l) {
  __shared__ __align__(16) unsigned char raw[49152];
  unsigned short* As = (unsigned short*)raw;            // 2 x 16384 B
  unsigned short* Bs = (unsigned short*)(raw + 32768);  // 2 x  8192 B
  float*          Gex = (float*)raw;                    // 33280 B (aliased)
  const int tid = threadIdx.x, lane = tid & 63, wave = tid >> 6;
  const int mbase = blockIdx.x * 128;
  const int h0    = blockIdx.y * 16;
  const unsigned short* Ab = hidden_ro + (size_t)(l - 1) * 1024;  // lda 4096
  const float*          Bl = Wg + (size_t)l * 4096 * 2560 + 1536; // lda 2560

  uint4  apf[2];
  float4 bpf[2];
  auto loadT = [&](int kt) {
    const int kg = kt * 64;
#pragma unroll
    for (int r = 0; r < 2; ++r) {
      const int row = (tid >> 3) + r * 64;
      apf[r] = *(const uint4*)(Ab + (size_t)(mbase + row) * 4096 + kg + (tid & 7) * 8);
    }
#pragma unroll
    for (int j = 0; j < 2; ++j) {
      const int idx = j * 512 + tid;
      const int nl = idx >> 4, kc = (idx & 15) * 4;
      const int grow = (nl >> 4) * 1024 + h0 + (nl & 15);
      bpf[j] = *(const float4*)(Bl + (size_t)grow * 2560 + kg + kc);
    }
  };
  auto storeT = [&](int buf) {
#pragma unroll
    for (int r = 0; r < 2; ++r) {
      const int row = (tid >> 3) + r * 64;
      *(uint4*)(&As[buf * 8192 + row * 64 + (((tid & 7) ^ (row & 7)) * 8)]) = apf[r];
    }
#pragma unroll
    for (int j = 0; j < 2; ++j) {
      const int idx = j * 512 + tid;
      const int nl = idx >> 4, kc = (idx & 15) * 4;
      uint2 pk;
      pk.x = f2bf2(bpf[j].x, bpf[j].y);
      pk.y = f2bf2(bpf[j].z, bpf[j].w);
      *(uint2*)(&Bs[buf * 4096 + nl * 64 + (((kc >> 3) ^ (nl & 7)) * 8) + (kc & 4)]) = pk;
    }
  };

  floatx16 acc;
#pragma unroll
  for (int r = 0; r < 16; ++r) acc[r] = 0.f;
  const int wm = (wave & 3) * 32, wn = (wave >> 2) * 32;

  loadT(0);
  storeT(0);
  __syncthreads();
  for (int kt = 0; kt < 16; ++kt) {
    if (kt + 1 < 16) loadT(kt + 1);
    const int cb = kt & 1;
    const int rowa = wm + (lane & 31);
    const int rowb = wn + (lane & 31);
#pragma unroll
    for (int ks = 0; ks < 4; ++ks) {
      const int gb = ks * 2 + (lane >> 5);
      const shortx8 af = *(const shortx8*)(&As[cb * 8192 + rowa * 64 + ((gb ^ (rowa & 7)) * 8)]);
      const shortx8 bfv = *(const shortx8*)(&Bs[cb * 4096 + rowb * 64 + ((gb ^ (rowb & 7)) * 8)]);
      acc = __builtin_amdgcn_mfma_f32_32x32x16_bf16(af, bfv, acc, 0, 0, 0);
    }
    if (kt + 1 < 16) storeT((kt + 1) & 1);
    __syncthreads();
  }

  // acc -> LDS (layout [b][n_local], pad 65)
  {
    const int col = wn + (lane & 31);
#pragma unroll
    for (int r = 0; r < 16; ++r) {
      const int row = wm + ((r & 3) + 8 * (r >> 2) + 4 * (lane >> 5));
      Gex[row * 65 + col] = acc[r];
    }
  }
  __syncthreads();

  // fused LSTM cell: 4 cells/thread over 128 b x 16 hh
  const int hh = tid & 15, q = tid >> 4;   // q in 0..31
#pragma unroll
  for (int bi = 0; bi < 4; ++bi) {
    const int bl = bi * 32 + q;
    const int b  = mbase + bl;
    const int hg = h0 + hh;
    const float* Gb = G + ((size_t)l * 512 + b) * 4096;
    float gv[4];
#pragma unroll
    for (int g = 0; g < 4; ++g)
      gv[g] = Gex[bl * 65 + g * 16 + hh] + Gb[g * 1024 + hg];
    const float c_old = c_prev[((size_t)l * 512 + b) * 1024 + hg];
    const float c  = sigm(gv[1]) * c_old + sigm(gv[0]) * tanh_(gv[3]);
    const float hn = sigm(gv[2]) * tanh_(c);
    hidden_w[(size_t)b * 4096 + l * 1024 + hg] = (unsigned short)f2bf1(hn);
  }
}

// ---------------------------------------------------------------------------
// gemm_heads: split-K GEMM over hidden[512][4096] x [W_y;W_E] -> partials.
// BM=BN=128 BK=64, dbuf, grid (8 ksplit, 6 n, 4 m), K=512 per split.
// ---------------------------------------------------------------------------
__global__ __launch_bounds__(256) void gemm_heads(
    const unsigned short* __restrict__ A, const float* __restrict__ Wy,
    const float* __restrict__ WE, float* __restrict__ Cp) {
  __shared__ __align__(16) unsigned short As[2][128 * 64];
  __shared__ __align__(16) unsigned short Bs[2][128 * 64];
  const int tid = threadIdx.x, lane = tid & 63, wave = tid >> 6;
  const int mbase = blockIdx.z * 128;
  const int nt    = blockIdx.y;
  const int nbase = nt * 128;
  const float* Bb = (nt < 4) ? (Wy + (size_t)nbase * 4096)
                             : (WE + (size_t)(nbase - 512) * 4096);
  const int k0 = blockIdx.x * 512;
  const unsigned short* Ab = A + (size_t)mbase * 4096;
  const int arow = wave * 8 + (lane >> 3);
  const int akg  = lane & 7;

  uint4  apf[4];
  float4 bpf[8];
  auto loadT = [&](int kt) {
    const int kg = k0 + kt * 64;
#pragma unroll
    for (int r = 0; r < 4; ++r)
      apf[r] = *(const uint4*)(Ab + (size_t)(arow + r * 32) * 4096 + kg + akg * 8);
#pragma unroll
    for (int j = 0; j < 8; ++j) {
      const int idx = j * 256 + tid;
      bpf[j] = *(const float4*)(Bb + (size_t)(idx >> 4) * 4096 + kg + (idx & 15) * 4);
    }
  };
  auto storeT = [&](int buf) {
#pragma unroll
    for (int r = 0; r < 4; ++r) {
      const int row = arow + r * 32;
      *(uint4*)(&As[buf][row * 64 + ((akg ^ (row & 7)) * 8)]) = apf[r];
    }
#pragma unroll
    for (int j = 0; j < 8; ++j) {
      const int idx = j * 256 + tid;
      const int n = idx >> 4, kc = (idx & 15) * 4;
      uint2 pk;
      pk.x = f2bf2(bpf[j].x, bpf[j].y);
      pk.y = f2bf2(bpf[j].z, bpf[j].w);
      *(uint2*)(&Bs[buf][n * 64 + (((kc >> 3) ^ (n & 7)) * 8) + (kc & 4)]) = pk;
    }
  };

  floatx16 acc[2][2];
#pragma unroll
  for (int a = 0; a < 2; ++a)
#pragma unroll
    for (int b2 = 0; b2 < 2; ++b2)
#pragma unroll
      for (int r = 0; r < 16; ++r) acc[a][b2][r] = 0.f;
  const int wm = (wave >> 1) * 64, wn = (wave & 1) * 64;

  loadT(0);
  storeT(0);
  __syncthreads();
  for (int kt = 0; kt < 8; ++kt) {
    if (kt + 1 < 8) loadT(kt + 1);
    const int cb = kt & 1;
#pragma unroll
    for (int ks = 0; ks < 4; ++ks) {
      const int gb = ks * 2 + (lane >> 5);
      shortx8 af[2], bfv[2];
#pragma unroll
      for (int sm = 0; sm < 2; ++sm) {
        const int row = wm + sm * 32 + (lane & 31);
        af[sm] = *(const shortx8*)(&As[cb][row * 64 + ((gb ^ (row & 7)) * 8)]);
      }
#pragma unroll
      for (int sn = 0; sn < 2; ++sn) {
        const int row = wn + sn * 32 + (lane & 31);
        bfv[sn] = *(const shortx8*)(&Bs[cb][row * 64 + ((gb ^ (row & 7)) * 8)]);
      }
#pragma unroll
      for (int sm = 0; sm < 2; ++sm)
#pragma unroll
        for (int sn = 0; sn < 2; ++sn)
          acc[sm][sn] = __builtin_amdgcn_mfma_f32_32x32x16_bf16(
              af[sm], bfv[sn], acc[sm][sn], 0, 0, 0);
    }
    if (kt + 1 < 8) storeT((kt + 1) & 1);
    __syncthreads();
  }

  float* Co = Cp + (size_t)blockIdx.x * 512 * 768;
#pragma unroll
  for (int sm = 0; sm < 2; ++sm)
#pragma unroll
    for (int sn = 0; sn < 2; ++sn) {
      const int col = nbase + wn + sn * 32 + (lane & 31);
#pragma unroll
      for (int r = 0; r < 16; ++r) {
        const int row = mbase + wm + sm * 32 +
                        ((r & 3) + 8 * (r >> 2) + 4 * (lane >> 5));
        Co[(size_t)row * 768 + col] = acc[sm][sn][r];
      }
    }
}

// ---------------------------------------------------------------------------
// head_reduce: sum 8 k-split partials + bias -> d_out.  grid (3,512) x 256
// ---------------------------------------------------------------------------
__global__ __launch_bounds__(256) void head_reduce(
    const float* __restrict__ hp, const float* __restrict__ b_y,
    const float* __restrict__ b_E, float* __restrict__ out) {
  const int n = blockIdx.x * 256 + threadIdx.x;  // 0..767
  const int b = blockIdx.y;
  float s = 0.f;
#pragma unroll
  for (int ks = 0; ks < 8; ++ks)
    s += hp[(size_t)ks * 512 * 768 + (size_t)b * 768 + n];
  if (n < 512)
    out[(size_t)b * 512 + n] = s + b_y[n];
  else
    out[(size_t)512 * 512 + (size_t)b * 256 + (n - 512)] = s + b_E[n - 512];
}

// ---------------------------------------------------------------------------
extern "C" void kernel_launch(void* const* d_in, const int* in_sizes, int n_in,
                              void* d_out, int out_size, void* d_ws, size_t ws_size,
                              hipStream_t stream) {
  const float* x      = (const float*)d_in[0];
  const float* h_prev = (const float*)d_in[1];
  const float* c_prev = (const float*)d_in[2];
  const float* Wg     = (const float*)d_in[3];
  const float* bg     = (const float*)d_in[4];
  const float* W_y    = (const float*)d_in[5];
  const float* b_y    = (const float*)d_in[6];
  const float* W_E    = (const float*)d_in[7];
  const float* b_E    = (const float*)d_in[8];

  char* ws = (char*)d_ws;
  unsigned short* A0     = (unsigned short*)(ws + 0);
  float*          G      = (float*)(ws + 6291456);
  unsigned short* hidden = (unsigned short*)(ws + 39845888);
  float*          hpart  = (float*)(ws + 44040192);

  prep_a0<<<dim3(384, 4), 256, 0, stream>>>(x, h_prev, A0);
  gemm_gates<<<dim3(4, 32, 4), 256, 0, stream>>>(A0, Wg, bg, G);
  cell0<<<512, 256, 0, stream>>>(G, c_prev, hidden);
  for (int l = 1; l < 4; ++l)
    gemm_seq_cell<<<dim3(4, 64), 512, 0, stream>>>(hidden, Wg, G, c_prev,
                                                   hidden, l);
  gemm_heads<<<dim3(8, 6, 4), 256, 0, stream>>>(hidden, W_y, W_E, hpart);
  head_reduce<<<dim3(3, 512), 256, 0, stream>>>(hpart, b_y, b_E, (float*)d_out);
}